// Round 3
// baseline (169.927 us; speedup 1.0000x reference)
//
#include <hip/hip_runtime.h>
#include <math.h>

// Problem constants: [N, L, H, D] = [4, 8192, 8, 64], Dv = 64, fp32 in/out.
#define N_    4
#define L_    8192
#define H_    8
#define NH_   32           // N*H
#define CHK   64           // chunk length
#define NSEG  32           // segments per (n,h)
#define SEGC  4            // chunks per segment  (NSEG*SEGC*CHK == L_)
#define ROWF  512          // H_*D_ floats between consecutive l
#define EPSF  1e-6f

typedef __attribute__((ext_vector_type(8))) short bf16x8;   // 8 bf16 = 4 VGPRs
typedef __attribute__((ext_vector_type(4))) float f32x4;
typedef __attribute__((ext_vector_type(4))) unsigned short us4;

__device__ __forceinline__ float fmap(float x) { return x > 0.f ? x + 1.f : __expf(x); }

__device__ __forceinline__ unsigned short f2bf(float x) {
  unsigned u = __float_as_uint(x);
  u += 0x7FFFu + ((u >> 16) & 1u);       // round-to-nearest-even
  return (unsigned short)(u >> 16);
}
__device__ __forceinline__ float bf2f(unsigned short u) {
  return __uint_as_float(((unsigned)u) << 16);
}

// Swizzled ushort index into a row-major [64] bf16 tile (row stride 128 B).
__device__ __forceinline__ int sidx(int row, int col) {
  return row * 64 + (col ^ ((row & 7) << 3));
}

__device__ __forceinline__ f32x4 MFMA(bf16x8 a, bf16x8 b, f32x4 c) {
  return __builtin_amdgcn_mfma_f32_16x16x32_bf16(a, b, c, 0, 0, 0);
}

// ---------------- Pass A: per-SEGMENT S^T = sum_c V^T K  and  ksum ----------------
__global__ __launch_bounds__(256) void k_seg_sums(const float* __restrict__ keys,
                                                  const float* __restrict__ values,
                                                  float* __restrict__ Sws,
                                                  float* __restrict__ Kws) {
  __shared__ unsigned short Kt[64 * 64];  // K^T [d][s] (fmap, bf16)
  __shared__ unsigned short Vt[64 * 64];  // V^T [e][s]
  __shared__ float kacc[64];
  const int bid = blockIdx.x;             // nh*NSEG + seg
  const int nh = bid / NSEG, seg = bid % NSEG;
  const int n = nh / H_, h = nh % H_;
  const int tid = threadIdx.x;
  const int lane = tid & 63;
  const int wv = tid >> 6;
  const int lane15 = lane & 15, lg = lane >> 4;
  const int arow = wv * 16 + lane15;

  if (tid < 64) kacc[tid] = 0.f;

  f32x4 sAcc[4];
#pragma unroll
  for (int nt = 0; nt < 4; ++nt) sAcc[nt] = (f32x4){0.f, 0.f, 0.f, 0.f};
  float kpart = 0.f;                       // colsum partial for column d = tid&63

  for (int ci = 0; ci < SEGC; ++ci) {
    const int l0 = (seg * SEGC + ci) * CHK;
    // transposed staging (thread owns column d, s-range [sg*16, sg*16+16))
    {
      const int d = tid & 63, sg = tid >> 6;
      const size_t gbase = ((size_t)(n * L_ + l0)) * ROWF + h * 64 + d;
      for (int rep = 0; rep < 4; ++rep) {
        const int s0 = (sg * 4 + rep) * 4;
        us4 wk, wvv;
#pragma unroll
        for (int j = 0; j < 4; ++j) {
          const size_t g = gbase + (size_t)(s0 + j) * ROWF;
          const float kf = fmap(keys[g]);
          kpart += kf;
          wk[j] = f2bf(kf);
          wvv[j] = f2bf(values[g]);
        }
        *(us4*)&Kt[sidx(d, s0)] = wk;
        *(us4*)&Vt[sidx(d, s0)] = wvv;
      }
    }
    __syncthreads();
    const bf16x8 av0 = *(const bf16x8*)&Vt[sidx(arow, lg * 8)];
    const bf16x8 av1 = *(const bf16x8*)&Vt[sidx(arow, (lg + 4) * 8)];
#pragma unroll
    for (int nt = 0; nt < 4; ++nt) {
      const int brow = nt * 16 + lane15;
      sAcc[nt] = MFMA(av0, *(const bf16x8*)&Kt[sidx(brow, lg * 8)], sAcc[nt]);
      sAcc[nt] = MFMA(av1, *(const bf16x8*)&Kt[sidx(brow, (lg + 4) * 8)], sAcc[nt]);
    }
    __syncthreads();  // before restaging
  }

  // write segment S^T (fp32) and ksum
  float* Sg = Sws + (size_t)bid * 4096;
#pragma unroll
  for (int nt = 0; nt < 4; ++nt) {
    const int e = wv * 16 + lg * 4;
    const int d = nt * 16 + lane15;
#pragma unroll
    for (int r = 0; r < 4; ++r) Sg[(size_t)(e + r) * 64 + d] = sAcc[nt][r];
  }
  atomicAdd(&kacc[tid & 63], kpart);
  __syncthreads();
  if (tid < 64) Kws[(size_t)bid * 64 + tid] = kacc[tid];
}

// ---------------- Pass B: exclusive prefix over segments (in place, fp32) ----------------
__global__ __launch_bounds__(256) void k_prefix(float* __restrict__ Sws, float* __restrict__ Kws) {
  const int tid = threadIdx.x;
  if (blockIdx.x < 512) {
    const int gid = blockIdx.x * 256 + tid;          // 0 .. 131071
    const int nh = gid >> 12, de = gid & 4095;
    float* p = Sws + (size_t)nh * NSEG * 4096 + de;
    float run = 0.f;
    for (int s = 0; s < NSEG; ++s) {
      const float x = p[(size_t)s * 4096];
      p[(size_t)s * 4096] = run;
      run += x;
    }
  } else {
    const int gid = (blockIdx.x - 512) * 256 + tid;  // 0 .. 2047
    const int nh = gid >> 6, d = gid & 63;
    float* p = Kws + (size_t)nh * NSEG * 64 + d;
    float run = 0.f;
    for (int s = 0; s < NSEG; ++s) {
      const float x = p[s * 64];
      p[s * 64] = run;
      run += x;
    }
  }
}

// ---------------- Pass C: fused scan over the segment's chunks ----------------
__global__ __launch_bounds__(256, 4) void k_scan_out(const float* __restrict__ queries,
                                                     const float* __restrict__ keys,
                                                     const float* __restrict__ values,
                                                     const float* __restrict__ Sws,
                                                     const float* __restrict__ Kws,
                                                     float* __restrict__ out) {
  __shared__ unsigned short Ks[64 * 64];  // K row-major (fmap); reused as attn tile
  __shared__ unsigned short Kt[64 * 64];  // K^T [d][s]
  __shared__ unsigned short Vt[64 * 64];  // V^T [e][s]
  __shared__ unsigned short St[64 * 64];  // running S^T [e][d], bf16 mirror
  __shared__ float kpre[64];              // running exclusive ksum
  __shared__ float zden_i[64];

  const int bid = blockIdx.x;             // nh*NSEG + seg
  const int nh = bid / NSEG, seg = bid % NSEG;
  const int n = nh / H_, h = nh % H_;
  const int tid = threadIdx.x;
  const int lane = tid & 63;
  const int wv = tid >> 6;
  const int lane15 = lane & 15, lg = lane >> 4;
  const int t0w = wv * 16;
  const int arow = t0w + lane15;

  // init running S^T from ws (exclusive segment prefix, fp32) into MFMA C-frags
  f32x4 sAcc[4];
  {
    const float* Sg = Sws + (size_t)bid * 4096;
#pragma unroll
    for (int nt = 0; nt < 4; ++nt)
#pragma unroll
      for (int r = 0; r < 4; ++r)
        sAcc[nt][r] = Sg[(size_t)(t0w + lg * 4 + r) * 64 + nt * 16 + lane15];
  }
  if (tid < 64) kpre[tid] = Kws[(size_t)bid * 64 + tid];
  // bf16 mirror of S^T for the Q*S MFMA operand
#pragma unroll
  for (int nt = 0; nt < 4; ++nt)
#pragma unroll
    for (int r = 0; r < 4; ++r)
      St[sidx(t0w + lg * 4 + r, nt * 16 + lane15)] = f2bf(sAcc[nt][r]);

  for (int ci = 0; ci < SEGC; ++ci) {
    const int l0 = (seg * SEGC + ci) * CHK;

    // ---- staging ----
    // K row-major (fmap, bf16) — coalesced float4
    {
      const int r0 = tid >> 4, c4 = (tid & 15) * 4;
      for (int rep = 0; rep < 4; ++rep) {
        const int row = r0 + rep * 16;
        const size_t g = ((size_t)(n * L_ + l0 + row)) * ROWF + h * 64 + c4;
        const float4 k = *(const float4*)&keys[g];
        us4 uk;
        uk[0] = f2bf(fmap(k.x)); uk[1] = f2bf(fmap(k.y));
        uk[2] = f2bf(fmap(k.z)); uk[3] = f2bf(fmap(k.w));
        *(us4*)&Ks[sidx(row, c4)] = uk;
      }
    }
    // K^T and V^T (transposed scalar loads) + kpre partial
    float kpart = 0.f;
    {
      const int d = tid & 63, sg = tid >> 6;
      const size_t gbase = ((size_t)(n * L_ + l0)) * ROWF + h * 64 + d;
      for (int rep = 0; rep < 4; ++rep) {
        const int s0 = (sg * 4 + rep) * 4;
        us4 wk, wvv;
#pragma unroll
        for (int j = 0; j < 4; ++j) {
          const size_t g = gbase + (size_t)(s0 + j) * ROWF;
          const float kf = fmap(keys[g]);
          kpart += kf;
          wk[j] = f2bf(kf);
          wvv[j] = f2bf(values[g]);
        }
        *(us4*)&Kt[sidx(d, s0)] = wk;
        *(us4*)&Vt[sidx(d, s0)] = wvv;
      }
    }
    // Q fragments: straight from global into registers (rows = arow)
    bf16x8 qf0, qf1;
    {
      const size_t qg = ((size_t)(n * L_ + l0 + arow)) * ROWF + h * 64;
      const float4 a = *(const float4*)&queries[qg + lg * 8];
      const float4 b = *(const float4*)&queries[qg + lg * 8 + 4];
      const float4 c = *(const float4*)&queries[qg + 32 + lg * 8];
      const float4 d4 = *(const float4*)&queries[qg + 32 + lg * 8 + 4];
      qf0[0] = (short)f2bf(fmap(a.x)); qf0[1] = (short)f2bf(fmap(a.y));
      qf0[2] = (short)f2bf(fmap(a.z)); qf0[3] = (short)f2bf(fmap(a.w));
      qf0[4] = (short)f2bf(fmap(b.x)); qf0[5] = (short)f2bf(fmap(b.y));
      qf0[6] = (short)f2bf(fmap(b.z)); qf0[7] = (short)f2bf(fmap(b.w));
      qf1[0] = (short)f2bf(fmap(c.x)); qf1[1] = (short)f2bf(fmap(c.y));
      qf1[2] = (short)f2bf(fmap(c.z)); qf1[3] = (short)f2bf(fmap(c.w));
      qf1[4] = (short)f2bf(fmap(d4.x)); qf1[5] = (short)f2bf(fmap(d4.y));
      qf1[6] = (short)f2bf(fmap(d4.z)); qf1[7] = (short)f2bf(fmap(d4.w));
    }
    __syncthreads();  // B1: staging visible (also orders St refresh / kpre updates)

    // ---- QK^T ----
    f32x4 attC[4];
#pragma unroll
    for (int nt = 0; nt < 4; ++nt) {
      const int brow = nt * 16 + lane15;
      f32x4 a = {0.f, 0.f, 0.f, 0.f};
      a = MFMA(qf0, *(const bf16x8*)&Ks[sidx(brow, lg * 8)], a);
      a = MFMA(qf1, *(const bf16x8*)&Ks[sidx(brow, (lg + 4) * 8)], a);
      attC[nt] = a;
    }
    // zden inter-chunk term: in-register dot Q[arow] . kpre
    {
      float zp = 0.f;
#pragma unroll
      for (int j = 0; j < 8; ++j) zp += bf2f((unsigned short)qf0[j]) * kpre[lg * 8 + j];
#pragma unroll
      for (int j = 0; j < 8; ++j) zp += bf2f((unsigned short)qf1[j]) * kpre[32 + lg * 8 + j];
      zp += __shfl_xor(zp, 16);
      zp += __shfl_xor(zp, 32);
      if (lane < 16) zden_i[t0w + lane15] = zp;   // same-wave consumers only
    }
    __syncthreads();  // B2: Ks reads done (becomes attn buffer); kpre reads done

    atomicAdd(&kpre[tid & 63], kpart);  // exclusive->next-chunk update (visible by next B1)

    // ---- mask + rowsum + zinv (registers) + attn->bf16 LDS ----
    float zinvr[4];
    {
      float rs[4] = {0.f, 0.f, 0.f, 0.f};
#pragma unroll
      for (int nt = 0; nt < 4; ++nt)
#pragma unroll
        for (int r = 0; r < 4; ++r) {
          const int t = t0w + lg * 4 + r;
          const int s = nt * 16 + lane15;
          const float v = (s <= t) ? attC[nt][r] : 0.f;
          rs[r] += v;
          Ks[sidx(t, s)] = f2bf(v);
        }
#pragma unroll
      for (int r = 0; r < 4; ++r) {
        float v = rs[r];
        v += __shfl_xor(v, 1);
        v += __shfl_xor(v, 2);
        v += __shfl_xor(v, 4);
        v += __shfl_xor(v, 8);
        zinvr[r] = 1.f / (v + zden_i[t0w + lg * 4 + r] + EPSF);
      }
    }
    __syncthreads();  // B3: attn visible

    // ---- phase B: out = attn*V + Q*S_old ; S^T += V^T K ----
    const bf16x8 af0 = *(const bf16x8*)&Ks[sidx(arow, lg * 8)];
    const bf16x8 af1 = *(const bf16x8*)&Ks[sidx(arow, (lg + 4) * 8)];
    const bf16x8 av0 = *(const bf16x8*)&Vt[sidx(arow, lg * 8)];
    const bf16x8 av1 = *(const bf16x8*)&Vt[sidx(arow, (lg + 4) * 8)];
#pragma unroll
    for (int nt = 0; nt < 4; ++nt) {
      const int brow = nt * 16 + lane15;
      f32x4 o = {0.f, 0.f, 0.f, 0.f};
      o = MFMA(af0, *(const bf16x8*)&Vt[sidx(brow, lg * 8)], o);
      o = MFMA(af1, *(const bf16x8*)&Vt[sidx(brow, (lg + 4) * 8)], o);
      o = MFMA(qf0, *(const bf16x8*)&St[sidx(brow, lg * 8)], o);
      o = MFMA(qf1, *(const bf16x8*)&St[sidx(brow, (lg + 4) * 8)], o);
      const int e = nt * 16 + lane15;
#pragma unroll
      for (int r = 0; r < 4; ++r) {
        const int t = t0w + lg * 4 + r;
        out[((size_t)(n * L_ + l0 + t)) * ROWF + h * 64 + e] = o[r] * zinvr[r];
      }
      // running state update (registers)
      sAcc[nt] = MFMA(av0, *(const bf16x8*)&Kt[sidx(brow, lg * 8)], sAcc[nt]);
      sAcc[nt] = MFMA(av1, *(const bf16x8*)&Kt[sidx(brow, (lg + 4) * 8)], sAcc[nt]);
    }
    __syncthreads();  // B4: all St/Vt/Kt/attn reads drained

    // refresh bf16 S^T mirror for next chunk
    if (ci + 1 < SEGC) {
#pragma unroll
      for (int nt = 0; nt < 4; ++nt)
#pragma unroll
        for (int r = 0; r < 4; ++r)
          St[sidx(t0w + lg * 4 + r, nt * 16 + lane15)] = f2bf(sAcc[nt][r]);
    }
  }
}

extern "C" void kernel_launch(void* const* d_in, const int* in_sizes, int n_in,
                              void* d_out, int out_size, void* d_ws, size_t ws_size,
                              hipStream_t stream) {
  const float* queries = (const float*)d_in[0];
  const float* keys    = (const float*)d_in[1];
  const float* values  = (const float*)d_in[2];
  float* out = (float*)d_out;

  // workspace: segment S^T sums [NH_*NSEG][64][64] then ksum [NH_*NSEG][64]
  const size_t s_elems = (size_t)NH_ * NSEG * 4096;
  const size_t k_elems = (size_t)NH_ * NSEG * 64;
  if (ws_size < (s_elems + k_elems) * sizeof(float)) return;
  float* Sws = (float*)d_ws;
  float* Kws = Sws + s_elems;

  hipLaunchKernelGGL(k_seg_sums, dim3(NH_ * NSEG), dim3(256), 0, stream, keys, values, Sws, Kws);
  hipLaunchKernelGGL(k_prefix, dim3(512 + 8), dim3(256), 0, stream, Sws, Kws);
  hipLaunchKernelGGL(k_scan_out, dim3(NH_ * NSEG), dim3(256), 0, stream,
                     queries, keys, values, Sws, Kws, out);
}

// Round 4
// 101.224 us; speedup vs baseline: 1.6787x; 1.6787x over previous
//
#include <hip/hip_runtime.h>
#include <math.h>

// Problem constants: [N, L, H, D] = [4, 8192, 8, 64], Dv = 64, fp32 in/out.
#define N_    4
#define L_    8192
#define H_    8
#define NH_   32           // N*H
#define CHK   64           // chunk length
#define NSEG  32           // segments per (n,h)
#define SEGC  4            // chunks per segment
#define NC_   128          // chunks per (n,h)
#define ROWF  512          // H_*D_ floats between consecutive l
#define EPSF  1e-6f

typedef __attribute__((ext_vector_type(8))) short bf16x8;   // 8 bf16 = 4 VGPRs
typedef __attribute__((ext_vector_type(4))) float f32x4;
typedef __attribute__((ext_vector_type(4))) unsigned short us4;

__device__ __forceinline__ float fmap(float x) { return x > 0.f ? x + 1.f : __expf(x); }

__device__ __forceinline__ unsigned short f2bf(float x) {
  unsigned u = __float_as_uint(x);
  u += 0x7FFFu + ((u >> 16) & 1u);       // round-to-nearest-even
  return (unsigned short)(u >> 16);
}
__device__ __forceinline__ float bf2f(unsigned short u) {
  return __uint_as_float(((unsigned)u) << 16);
}

// Swizzled ushort index into a row-major [64] bf16 tile (row stride 128 B).
__device__ __forceinline__ int sidx(int row, int col) {
  return row * 64 + (col ^ ((row & 7) << 3));
}

__device__ __forceinline__ f32x4 MFMA(bf16x8 a, bf16x8 b, f32x4 c) {
  return __builtin_amdgcn_mfma_f32_16x16x32_bf16(a, b, c, 0, 0, 0);
}

// ---------------- Pass A: segment sums + per-chunk intra-segment exclusive prefixes ----------------
__global__ __launch_bounds__(256) void k_seg_sums(const float* __restrict__ keys,
                                                  const float* __restrict__ values,
                                                  float* __restrict__ SegTot,
                                                  unsigned short* __restrict__ IntraPre,
                                                  float* __restrict__ KsegTot,
                                                  float* __restrict__ KintraPre) {
  __shared__ unsigned short Kt[64 * 64];  // K^T [d][s] (fmap, bf16)
  __shared__ unsigned short Vt[64 * 64];  // V^T [e][s]
  __shared__ float kacc[64];
  const int bid = blockIdx.x;             // nh*NSEG + seg
  const int nh = bid / NSEG, seg = bid % NSEG;
  const int n = nh / H_, h = nh % H_;
  const int tid = threadIdx.x;
  const int lane = tid & 63;
  const int wv = tid >> 6;
  const int lane15 = lane & 15, lg = lane >> 4;
  const int arow = wv * 16 + lane15;

  if (tid < 64) kacc[tid] = 0.f;
  __syncthreads();

  f32x4 sAcc[4];
#pragma unroll
  for (int nt = 0; nt < 4; ++nt) sAcc[nt] = (f32x4){0.f, 0.f, 0.f, 0.f};

  for (int ci = 0; ci < SEGC; ++ci) {
    const int c = seg * SEGC + ci;
    const int l0 = c * CHK;
    float kpart = 0.f;
    // transposed staging (thread owns column d)
    {
      const int d = tid & 63, sg = tid >> 6;
      const size_t gbase = ((size_t)(n * L_ + l0)) * ROWF + h * 64 + d;
      for (int rep = 0; rep < 4; ++rep) {
        const int s0 = (sg * 4 + rep) * 4;
        us4 wk, wvv;
#pragma unroll
        for (int j = 0; j < 4; ++j) {
          const size_t g = gbase + (size_t)(s0 + j) * ROWF;
          const float kf = fmap(keys[g]);
          kpart += kf;
          wk[j] = f2bf(kf);
          wvv[j] = f2bf(values[g]);
        }
        *(us4*)&Kt[sidx(d, s0)] = wk;
        *(us4*)&Vt[sidx(d, s0)] = wvv;
      }
    }
    // exclusive intra-segment prefix for this chunk (register state, pre-update)
    {
      unsigned short* ip = IntraPre + ((size_t)nh * NC_ + c) * 4096;
#pragma unroll
      for (int nt = 0; nt < 4; ++nt)
#pragma unroll
        for (int r = 0; r < 4; ++r)
          ip[(size_t)(wv * 16 + lg * 4 + r) * 64 + nt * 16 + lane15] = f2bf(sAcc[nt][r]);
    }
    if (tid < 64) KintraPre[((size_t)nh * NC_ + c) * 64 + tid] = kacc[tid];
    __syncthreads();  // B1: staging + kacc-read done

    atomicAdd(&kacc[tid & 63], kpart);

    const bf16x8 av0 = *(const bf16x8*)&Vt[sidx(arow, lg * 8)];
    const bf16x8 av1 = *(const bf16x8*)&Vt[sidx(arow, (lg + 4) * 8)];
#pragma unroll
    for (int nt = 0; nt < 4; ++nt) {
      const int brow = nt * 16 + lane15;
      sAcc[nt] = MFMA(av0, *(const bf16x8*)&Kt[sidx(brow, lg * 8)], sAcc[nt]);
      sAcc[nt] = MFMA(av1, *(const bf16x8*)&Kt[sidx(brow, (lg + 4) * 8)], sAcc[nt]);
    }
    __syncthreads();  // B2: Kt/Vt reads + atomics drained before restage
  }

  float* Sg = SegTot + (size_t)bid * 4096;
#pragma unroll
  for (int nt = 0; nt < 4; ++nt)
#pragma unroll
    for (int r = 0; r < 4; ++r)
      Sg[(size_t)(wv * 16 + lg * 4 + r) * 64 + nt * 16 + lane15] = sAcc[nt][r];
  if (tid < 64) KsegTot[(size_t)bid * 64 + tid] = kacc[tid];
}

// ---------------- Pass B: exclusive prefix over segment totals (in place) ----------------
__global__ __launch_bounds__(256) void k_prefix(float* __restrict__ SegTot, float* __restrict__ KsegTot) {
  const int tid = threadIdx.x;
  if (blockIdx.x < 512) {
    const int gid = blockIdx.x * 256 + tid;          // 0 .. 131071
    const int nh = gid >> 12, de = gid & 4095;
    float* p = SegTot + (size_t)nh * NSEG * 4096 + de;
    float run = 0.f;
    for (int s = 0; s < NSEG; ++s) {
      const float x = p[(size_t)s * 4096];
      p[(size_t)s * 4096] = run;
      run += x;
    }
  } else {
    const int gid = (blockIdx.x - 512) * 256 + tid;  // 0 .. 2047
    const int nh = gid >> 6, d = gid & 63;
    float* p = KsegTot + (size_t)nh * NSEG * 64 + d;
    float run = 0.f;
    for (int s = 0; s < NSEG; ++s) {
      const float x = p[s * 64];
      p[s * 64] = run;
      run += x;
    }
  }
}

// ---------------- Pass C: per-chunk output (4096 blocks) ----------------
__global__ __launch_bounds__(256, 6) void k_output(const float* __restrict__ queries,
                                                   const float* __restrict__ keys,
                                                   const float* __restrict__ values,
                                                   const float* __restrict__ SegPre,
                                                   const unsigned short* __restrict__ IntraPre,
                                                   const float* __restrict__ KsegPre,
                                                   const float* __restrict__ KintraPre,
                                                   float* __restrict__ out) {
  __shared__ unsigned short Ks[64 * 64];  // K row-major (fmap); reused as attn tile
  __shared__ unsigned short Vt[64 * 64];  // V^T [e][s]
  __shared__ unsigned short St[64 * 64];  // S^T prefix [e][d] bf16
  __shared__ float kpre[64];
  __shared__ float zden_i[64];

  const int bid = blockIdx.x;             // nh*NC_ + c
  const int nh = bid / NC_, c = bid % NC_;
  const int seg = c / SEGC;
  const int n = nh / H_, h = nh % H_;
  const int tid = threadIdx.x;
  const int lane = tid & 63;
  const int wv = tid >> 6;
  const int lane15 = lane & 15, lg = lane >> 4;
  const int t0w = wv * 16;
  const int arow = t0w + lane15;
  const int l0 = c * CHK;

  // ---- staging ----
  // K row-major (fmap, bf16)
  {
    const int r0 = tid >> 4, c4 = (tid & 15) * 4;
    for (int rep = 0; rep < 4; ++rep) {
      const int row = r0 + rep * 16;
      const size_t g = ((size_t)(n * L_ + l0 + row)) * ROWF + h * 64 + c4;
      const float4 k = *(const float4*)&keys[g];
      us4 uk;
      uk[0] = f2bf(fmap(k.x)); uk[1] = f2bf(fmap(k.y));
      uk[2] = f2bf(fmap(k.z)); uk[3] = f2bf(fmap(k.w));
      *(us4*)&Ks[sidx(row, c4)] = uk;
    }
  }
  // V^T (transposed, coalesced across lanes)
  {
    const int d = tid & 63, sg = tid >> 6;
    const size_t gbase = ((size_t)(n * L_ + l0)) * ROWF + h * 64 + d;
    for (int rep = 0; rep < 4; ++rep) {
      const int s0 = (sg * 4 + rep) * 4;
      us4 w;
#pragma unroll
      for (int j = 0; j < 4; ++j) w[j] = f2bf(values[gbase + (size_t)(s0 + j) * ROWF]);
      *(us4*)&Vt[sidx(d, s0)] = w;
    }
  }
  // S^T prefix = SegPre (fp32) + IntraPre (bf16)
  {
    const float* sp = SegPre + ((size_t)nh * NSEG + seg) * 4096;
    const unsigned short* ip = IntraPre + ((size_t)nh * NC_ + c) * 4096;
    const int r0 = tid >> 4, c4 = (tid & 15) * 4;
    for (int rep = 0; rep < 4; ++rep) {
      const int row = r0 + rep * 16;
      const float4 s4 = *(const float4*)&sp[row * 64 + c4];
      const us4 i4 = *(const us4*)&ip[row * 64 + c4];
      us4 w;
      w[0] = f2bf(s4.x + bf2f(i4[0]));
      w[1] = f2bf(s4.y + bf2f(i4[1]));
      w[2] = f2bf(s4.z + bf2f(i4[2]));
      w[3] = f2bf(s4.w + bf2f(i4[3]));
      *(us4*)&St[sidx(row, c4)] = w;
    }
  }
  if (tid < 64)
    kpre[tid] = KsegPre[((size_t)nh * NSEG + seg) * 64 + tid] +
                KintraPre[((size_t)nh * NC_ + c) * 64 + tid];
  // Q fragments straight into registers
  bf16x8 qf0, qf1;
  {
    const size_t qg = ((size_t)(n * L_ + l0 + arow)) * ROWF + h * 64;
    const float4 a = *(const float4*)&queries[qg + lg * 8];
    const float4 b = *(const float4*)&queries[qg + lg * 8 + 4];
    const float4 cc = *(const float4*)&queries[qg + 32 + lg * 8];
    const float4 d4 = *(const float4*)&queries[qg + 32 + lg * 8 + 4];
    qf0[0] = (short)f2bf(fmap(a.x)); qf0[1] = (short)f2bf(fmap(a.y));
    qf0[2] = (short)f2bf(fmap(a.z)); qf0[3] = (short)f2bf(fmap(a.w));
    qf0[4] = (short)f2bf(fmap(b.x)); qf0[5] = (short)f2bf(fmap(b.y));
    qf0[6] = (short)f2bf(fmap(b.z)); qf0[7] = (short)f2bf(fmap(b.w));
    qf1[0] = (short)f2bf(fmap(cc.x)); qf1[1] = (short)f2bf(fmap(cc.y));
    qf1[2] = (short)f2bf(fmap(cc.z)); qf1[3] = (short)f2bf(fmap(cc.w));
    qf1[4] = (short)f2bf(fmap(d4.x)); qf1[5] = (short)f2bf(fmap(d4.y));
    qf1[6] = (short)f2bf(fmap(d4.z)); qf1[7] = (short)f2bf(fmap(d4.w));
  }
  __syncthreads();  // B1: all tiles + kpre visible

  // ---- QK^T ----
  f32x4 attC[4];
#pragma unroll
  for (int nt = 0; nt < 4; ++nt) {
    const int brow = nt * 16 + lane15;
    f32x4 a = {0.f, 0.f, 0.f, 0.f};
    a = MFMA(qf0, *(const bf16x8*)&Ks[sidx(brow, lg * 8)], a);
    a = MFMA(qf1, *(const bf16x8*)&Ks[sidx(brow, (lg + 4) * 8)], a);
    attC[nt] = a;
  }
  // zden inter-chunk term: in-register dot Q[arow] . kpre
  {
    float zp = 0.f;
#pragma unroll
    for (int j = 0; j < 8; ++j) zp += bf2f((unsigned short)qf0[j]) * kpre[lg * 8 + j];
#pragma unroll
    for (int j = 0; j < 8; ++j) zp += bf2f((unsigned short)qf1[j]) * kpre[32 + lg * 8 + j];
    zp += __shfl_xor(zp, 16);
    zp += __shfl_xor(zp, 32);
    if (lane < 16) zden_i[t0w + lane15] = zp;   // same-wave consumers only
  }
  __syncthreads();  // B2: Ks reads done (becomes attn buffer)

  // ---- mask + rowsum + zinv (registers) + attn->bf16 LDS ----
  float zinvr[4];
  {
    float rs[4] = {0.f, 0.f, 0.f, 0.f};
#pragma unroll
    for (int nt = 0; nt < 4; ++nt)
#pragma unroll
      for (int r = 0; r < 4; ++r) {
        const int t = t0w + lg * 4 + r;
        const int s = nt * 16 + lane15;
        const float v = (s <= t) ? attC[nt][r] : 0.f;
        rs[r] += v;
        Ks[sidx(t, s)] = f2bf(v);
      }
#pragma unroll
    for (int r = 0; r < 4; ++r) {
      float v = rs[r];
      v += __shfl_xor(v, 1);
      v += __shfl_xor(v, 2);
      v += __shfl_xor(v, 4);
      v += __shfl_xor(v, 8);
      zinvr[r] = 1.f / (v + zden_i[t0w + lg * 4 + r] + EPSF);
    }
  }
  __syncthreads();  // B3: attn visible

  // ---- out = attn*V + Q*S ----
  const bf16x8 af0 = *(const bf16x8*)&Ks[sidx(arow, lg * 8)];
  const bf16x8 af1 = *(const bf16x8*)&Ks[sidx(arow, (lg + 4) * 8)];
#pragma unroll
  for (int nt = 0; nt < 4; ++nt) {
    const int brow = nt * 16 + lane15;
    f32x4 o = {0.f, 0.f, 0.f, 0.f};
    o = MFMA(af0, *(const bf16x8*)&Vt[sidx(brow, lg * 8)], o);
    o = MFMA(af1, *(const bf16x8*)&Vt[sidx(brow, (lg + 4) * 8)], o);
    o = MFMA(qf0, *(const bf16x8*)&St[sidx(brow, lg * 8)], o);
    o = MFMA(qf1, *(const bf16x8*)&St[sidx(brow, (lg + 4) * 8)], o);
    const int e = nt * 16 + lane15;
#pragma unroll
    for (int r = 0; r < 4; ++r) {
      const int t = t0w + lg * 4 + r;
      out[((size_t)(n * L_ + l0 + t)) * ROWF + h * 64 + e] = o[r] * zinvr[r];
    }
  }
}

extern "C" void kernel_launch(void* const* d_in, const int* in_sizes, int n_in,
                              void* d_out, int out_size, void* d_ws, size_t ws_size,
                              hipStream_t stream) {
  const float* queries = (const float*)d_in[0];
  const float* keys    = (const float*)d_in[1];
  const float* values  = (const float*)d_in[2];
  float* out = (float*)d_out;

  // workspace layout:
  //  SegTot   [NH_*NSEG][4096] fp32   (totals -> exclusive prefix in pass B)
  //  IntraPre [NH_*NC_ ][4096] bf16   (per-chunk intra-segment exclusive prefix)
  //  KsegTot  [NH_*NSEG][64]   fp32
  //  KintraPre[NH_*NC_ ][64]   fp32
  const size_t segtot_e = (size_t)NH_ * NSEG * 4096;
  const size_t intra_e  = (size_t)NH_ * NC_ * 4096;
  const size_t kseg_e   = (size_t)NH_ * NSEG * 64;
  const size_t kintra_e = (size_t)NH_ * NC_ * 64;
  const size_t need = segtot_e * 4 + intra_e * 2 + kseg_e * 4 + kintra_e * 4;
  if (ws_size < need) return;
  float* SegTot = (float*)d_ws;
  unsigned short* IntraPre = (unsigned short*)(SegTot + segtot_e);
  float* KsegTot = (float*)(IntraPre + intra_e);
  float* KintraPre = KsegTot + kseg_e;

  hipLaunchKernelGGL(k_seg_sums, dim3(NH_ * NSEG), dim3(256), 0, stream,
                     keys, values, SegTot, IntraPre, KsegTot, KintraPre);
  hipLaunchKernelGGL(k_prefix, dim3(512 + 8), dim3(256), 0, stream, SegTot, KsegTot);
  hipLaunchKernelGGL(k_output, dim3(NH_ * NC_), dim3(256), 0, stream,
                     queries, keys, values, SegTot, IntraPre, KsegTot, KintraPre, out);
}

// Round 5
// 101.205 us; speedup vs baseline: 1.6790x; 1.0002x over previous
//
#include <hip/hip_runtime.h>
#include <math.h>

// Problem constants: [N, L, H, D] = [4, 8192, 8, 64], Dv = 64, fp32 in/out.
#define N_    4
#define L_    8192
#define H_    8
#define NH_   32           // N*H
#define CHK   64           // chunk length
#define NSEG  32           // segments per (n,h)
#define SEGC  4            // chunks per segment
#define NC_   128          // chunks per (n,h)
#define ROWF  512          // H_*D_ floats between consecutive l
#define EPSF  1e-6f

typedef __attribute__((ext_vector_type(8))) short bf16x8;   // 8 bf16 = 4 VGPRs
typedef __attribute__((ext_vector_type(4))) float f32x4;
typedef __attribute__((ext_vector_type(4))) unsigned short us4;

__device__ __forceinline__ float fmap(float x) { return x > 0.f ? x + 1.f : __expf(x); }

__device__ __forceinline__ unsigned short f2bf(float x) {
  unsigned u = __float_as_uint(x);
  u += 0x7FFFu + ((u >> 16) & 1u);       // round-to-nearest-even
  return (unsigned short)(u >> 16);
}
__device__ __forceinline__ float bf2f(unsigned short u) {
  return __uint_as_float(((unsigned)u) << 16);
}

// Swizzled ushort index into a row-major [64] bf16 tile (row stride 128 B).
__device__ __forceinline__ int sidx(int row, int col) {
  return row * 64 + (col ^ ((row & 7) << 3));
}

__device__ __forceinline__ f32x4 MFMA(bf16x8 a, bf16x8 b, f32x4 c) {
  return __builtin_amdgcn_mfma_f32_16x16x32_bf16(a, b, c, 0, 0, 0);
}

// ---------------- Pass A: segment sums + per-chunk intra-segment exclusive prefixes ----------------
__global__ __launch_bounds__(256) void k_seg_sums(const float* __restrict__ keys,
                                                  const float* __restrict__ values,
                                                  float* __restrict__ SegTot,
                                                  unsigned short* __restrict__ IntraPre,
                                                  float* __restrict__ KsegTot,
                                                  float* __restrict__ KintraPre) {
  __shared__ unsigned short Kt[64 * 64];  // K^T [d][s] (fmap, bf16)
  __shared__ unsigned short Vt[64 * 64];  // V^T [e][s]
  __shared__ float kacc[64];
  const int bid = blockIdx.x;             // nh*NSEG + seg
  const int nh = bid / NSEG, seg = bid % NSEG;
  const int n = nh / H_, h = nh % H_;
  const int tid = threadIdx.x;
  const int lane = tid & 63;
  const int wv = tid >> 6;
  const int lane15 = lane & 15, lg = lane >> 4;
  const int arow = wv * 16 + lane15;

  if (tid < 64) kacc[tid] = 0.f;
  __syncthreads();

  f32x4 sAcc[4];
#pragma unroll
  for (int nt = 0; nt < 4; ++nt) sAcc[nt] = (f32x4){0.f, 0.f, 0.f, 0.f};

  for (int ci = 0; ci < SEGC; ++ci) {
    const int c = seg * SEGC + ci;
    const int l0 = c * CHK;
    float kpart = 0.f;
    // transposed staging (thread owns column d)
    {
      const int d = tid & 63, sg = tid >> 6;
      const size_t gbase = ((size_t)(n * L_ + l0)) * ROWF + h * 64 + d;
      for (int rep = 0; rep < 4; ++rep) {
        const int s0 = (sg * 4 + rep) * 4;
        us4 wk, wvv;
#pragma unroll
        for (int j = 0; j < 4; ++j) {
          const size_t g = gbase + (size_t)(s0 + j) * ROWF;
          const float kf = fmap(keys[g]);
          kpart += kf;
          wk[j] = f2bf(kf);
          wvv[j] = f2bf(values[g]);
        }
        *(us4*)&Kt[sidx(d, s0)] = wk;
        *(us4*)&Vt[sidx(d, s0)] = wvv;
      }
    }
    // exclusive intra-segment prefix for this chunk (register state, pre-update)
    {
      unsigned short* ip = IntraPre + ((size_t)nh * NC_ + c) * 4096;
#pragma unroll
      for (int nt = 0; nt < 4; ++nt)
#pragma unroll
        for (int r = 0; r < 4; ++r)
          ip[(size_t)(wv * 16 + lg * 4 + r) * 64 + nt * 16 + lane15] = f2bf(sAcc[nt][r]);
    }
    if (tid < 64) KintraPre[((size_t)nh * NC_ + c) * 64 + tid] = kacc[tid];
    __syncthreads();  // B1: staging + kacc-read done

    atomicAdd(&kacc[tid & 63], kpart);

    const bf16x8 av0 = *(const bf16x8*)&Vt[sidx(arow, lg * 8)];
    const bf16x8 av1 = *(const bf16x8*)&Vt[sidx(arow, (lg + 4) * 8)];
#pragma unroll
    for (int nt = 0; nt < 4; ++nt) {
      const int brow = nt * 16 + lane15;
      sAcc[nt] = MFMA(av0, *(const bf16x8*)&Kt[sidx(brow, lg * 8)], sAcc[nt]);
      sAcc[nt] = MFMA(av1, *(const bf16x8*)&Kt[sidx(brow, (lg + 4) * 8)], sAcc[nt]);
    }
    __syncthreads();  // B2: Kt/Vt reads + atomics drained before restage
  }

  float* Sg = SegTot + (size_t)bid * 4096;
#pragma unroll
  for (int nt = 0; nt < 4; ++nt)
#pragma unroll
    for (int r = 0; r < 4; ++r)
      Sg[(size_t)(wv * 16 + lg * 4 + r) * 64 + nt * 16 + lane15] = sAcc[nt][r];
  if (tid < 64) KsegTot[(size_t)bid * 64 + tid] = kacc[tid];
}

// ---------------- Pass B: exclusive prefix over segment totals (in place) ----------------
__global__ __launch_bounds__(256) void k_prefix(float* __restrict__ SegTot, float* __restrict__ KsegTot) {
  const int tid = threadIdx.x;
  if (blockIdx.x < 512) {
    const int gid = blockIdx.x * 256 + tid;          // 0 .. 131071
    const int nh = gid >> 12, de = gid & 4095;
    float* p = SegTot + (size_t)nh * NSEG * 4096 + de;
    float run = 0.f;
    for (int s = 0; s < NSEG; ++s) {
      const float x = p[(size_t)s * 4096];
      p[(size_t)s * 4096] = run;
      run += x;
    }
  } else {
    const int gid = (blockIdx.x - 512) * 256 + tid;  // 0 .. 2047
    const int nh = gid >> 6, d = gid & 63;
    float* p = KsegTot + (size_t)nh * NSEG * 64 + d;
    float run = 0.f;
    for (int s = 0; s < NSEG; ++s) {
      const float x = p[s * 64];
      p[s * 64] = run;
      run += x;
    }
  }
}

// ---------------- Pass C: per-chunk output (4096 blocks) ----------------
__global__ __launch_bounds__(256, 6) void k_output(const float* __restrict__ queries,
                                                   const float* __restrict__ keys,
                                                   const float* __restrict__ values,
                                                   const float* __restrict__ SegPre,
                                                   const unsigned short* __restrict__ IntraPre,
                                                   const float* __restrict__ KsegPre,
                                                   const float* __restrict__ KintraPre,
                                                   float* __restrict__ out) {
  __shared__ unsigned short Ks[64 * 64];  // K row-major (fmap); after B2: attn rows (wave-local)
  __shared__ unsigned short Vt[64 * 64];  // V^T [e][s]
  __shared__ unsigned short St[64 * 64];  // S^T prefix [e][d] bf16
  __shared__ float kpre[64];
  __shared__ float zinv[64];              // wave-local broadcast (rows t0w..t0w+15 per wave)

  const int bid = blockIdx.x;             // nh*NC_ + c
  const int nh = bid / NC_, c = bid % NC_;
  const int seg = c / SEGC;
  const int n = nh / H_, h = nh % H_;
  const int tid = threadIdx.x;
  const int lane = tid & 63;
  const int wv = tid >> 6;
  const int lane15 = lane & 15, lg = lane >> 4;
  const int t0w = wv * 16;
  const int trow = t0w + lane15;          // this lane's attn row (wave-local)
  const int l0 = c * CHK;

  // ---- staging ----
  // K row-major (fmap, bf16)
  {
    const int r0 = tid >> 4, c4 = (tid & 15) * 4;
    for (int rep = 0; rep < 4; ++rep) {
      const int row = r0 + rep * 16;
      const size_t g = ((size_t)(n * L_ + l0 + row)) * ROWF + h * 64 + c4;
      const float4 k = *(const float4*)&keys[g];
      us4 uk;
      uk[0] = f2bf(fmap(k.x)); uk[1] = f2bf(fmap(k.y));
      uk[2] = f2bf(fmap(k.z)); uk[3] = f2bf(fmap(k.w));
      *(us4*)&Ks[sidx(row, c4)] = uk;
    }
  }
  // V^T (transposed, coalesced across lanes)
  {
    const int d = tid & 63, sg = tid >> 6;
    const size_t gbase = ((size_t)(n * L_ + l0)) * ROWF + h * 64 + d;
    for (int rep = 0; rep < 4; ++rep) {
      const int s0 = (sg * 4 + rep) * 4;
      us4 w;
#pragma unroll
      for (int j = 0; j < 4; ++j) w[j] = f2bf(values[gbase + (size_t)(s0 + j) * ROWF]);
      *(us4*)&Vt[sidx(d, s0)] = w;
    }
  }
  // S^T prefix = SegPre (fp32) + IntraPre (bf16)
  {
    const float* sp = SegPre + ((size_t)nh * NSEG + seg) * 4096;
    const unsigned short* ip = IntraPre + ((size_t)nh * NC_ + c) * 4096;
    const int r0 = tid >> 4, c4 = (tid & 15) * 4;
    for (int rep = 0; rep < 4; ++rep) {
      const int row = r0 + rep * 16;
      const float4 s4 = *(const float4*)&sp[row * 64 + c4];
      const us4 i4 = *(const us4*)&ip[row * 64 + c4];
      us4 w;
      w[0] = f2bf(s4.x + bf2f(i4[0]));
      w[1] = f2bf(s4.y + bf2f(i4[1]));
      w[2] = f2bf(s4.z + bf2f(i4[2]));
      w[3] = f2bf(s4.w + bf2f(i4[3]));
      *(us4*)&St[sidx(row, c4)] = w;
    }
  }
  if (tid < 64)
    kpre[tid] = KsegPre[((size_t)nh * NSEG + seg) * 64 + tid] +
                KintraPre[((size_t)nh * NC_ + c) * 64 + tid];
  // Q fragments straight into registers (row trow, k-slices lg*8 / 32+lg*8)
  bf16x8 qf0, qf1;
  {
    const size_t qg = ((size_t)(n * L_ + l0 + trow)) * ROWF + h * 64;
    const float4 a = *(const float4*)&queries[qg + lg * 8];
    const float4 b = *(const float4*)&queries[qg + lg * 8 + 4];
    const float4 cc = *(const float4*)&queries[qg + 32 + lg * 8];
    const float4 d4 = *(const float4*)&queries[qg + 32 + lg * 8 + 4];
    qf0[0] = (short)f2bf(fmap(a.x)); qf0[1] = (short)f2bf(fmap(a.y));
    qf0[2] = (short)f2bf(fmap(a.z)); qf0[3] = (short)f2bf(fmap(a.w));
    qf0[4] = (short)f2bf(fmap(b.x)); qf0[5] = (short)f2bf(fmap(b.y));
    qf0[6] = (short)f2bf(fmap(b.z)); qf0[7] = (short)f2bf(fmap(b.w));
    qf1[0] = (short)f2bf(fmap(cc.x)); qf1[1] = (short)f2bf(fmap(cc.y));
    qf1[2] = (short)f2bf(fmap(cc.z)); qf1[3] = (short)f2bf(fmap(cc.w));
    qf1[4] = (short)f2bf(fmap(d4.x)); qf1[5] = (short)f2bf(fmap(d4.y));
    qf1[6] = (short)f2bf(fmap(d4.z)); qf1[7] = (short)f2bf(fmap(d4.w));
  }
  __syncthreads();  // B1: all tiles + kpre visible

  // ---- QK^T, SWAPPED: attnT tile = MFMA(A=K rows s, B=Q rows t) ----
  // C-frag: lane (lg,m) reg r holds attn[t = t0w + m][s = nt*16 + lg*4 + r]
  f32x4 aT[4];
#pragma unroll
  for (int nt = 0; nt < 4; ++nt) {
    const int srow = nt * 16 + lane15;
    f32x4 a = {0.f, 0.f, 0.f, 0.f};
    a = MFMA(*(const bf16x8*)&Ks[sidx(srow, lg * 8)], qf0, a);
    a = MFMA(*(const bf16x8*)&Ks[sidx(srow, (lg + 4) * 8)], qf1, a);
    aT[nt] = a;
  }
  // zden inter-chunk term: in-register dot Q[trow] . kpre (partial over this lane's d-slice)
  float zp = 0.f;
#pragma unroll
  for (int j = 0; j < 8; ++j) zp += bf2f((unsigned short)qf0[j]) * kpre[lg * 8 + j];
#pragma unroll
  for (int j = 0; j < 8; ++j) zp += bf2f((unsigned short)qf1[j]) * kpre[32 + lg * 8 + j];

  __syncthreads();  // B2: all waves' Ks reads done (no outstanding vmem -> cheap drain)

  // ---- mask + rowsum + attn rows into Ks (wave-local rows) ----
  float rs = 0.f;
#pragma unroll
  for (int nt = 0; nt < 4; ++nt) {
    us4 w;
#pragma unroll
    for (int r = 0; r < 4; ++r) {
      const int s = nt * 16 + lg * 4 + r;
      const float v = (s <= trow) ? aT[nt][r] : 0.f;
      rs += v;
      w[r] = f2bf(v);
    }
    *(us4*)&Ks[sidx(trow, nt * 16 + lg * 4)] = w;
  }
  // full rowsum + zden for row trow: reduce the 4 lg-partials
  float den = rs + zp;
  den += __shfl_xor(den, 16);
  den += __shfl_xor(den, 32);
  const float zv = 1.f / (den + EPSF);
  if (lg == 0) zinv[trow] = zv;   // wave-local broadcast, consumed by same wave

  // ---- out = attn*V + Q*S  (attn A-frags re-read from wave-local rows) ----
  const bf16x8 af0 = *(const bf16x8*)&Ks[sidx(trow, lg * 8)];
  const bf16x8 af1 = *(const bf16x8*)&Ks[sidx(trow, 32 + lg * 8)];
#pragma unroll
  for (int nt = 0; nt < 4; ++nt) {
    const int brow = nt * 16 + lane15;
    f32x4 o = {0.f, 0.f, 0.f, 0.f};
    o = MFMA(af0, *(const bf16x8*)&Vt[sidx(brow, lg * 8)], o);
    o = MFMA(af1, *(const bf16x8*)&Vt[sidx(brow, (lg + 4) * 8)], o);
    o = MFMA(qf0, *(const bf16x8*)&St[sidx(brow, lg * 8)], o);
    o = MFMA(qf1, *(const bf16x8*)&St[sidx(brow, (lg + 4) * 8)], o);
    const int e = nt * 16 + lane15;
#pragma unroll
    for (int r = 0; r < 4; ++r) {
      const int t = t0w + lg * 4 + r;
      out[((size_t)(n * L_ + l0 + t)) * ROWF + h * 64 + e] = o[r] * zinv[t];
    }
  }
}

extern "C" void kernel_launch(void* const* d_in, const int* in_sizes, int n_in,
                              void* d_out, int out_size, void* d_ws, size_t ws_size,
                              hipStream_t stream) {
  const float* queries = (const float*)d_in[0];
  const float* keys    = (const float*)d_in[1];
  const float* values  = (const float*)d_in[2];
  float* out = (float*)d_out;

  // workspace layout:
  //  SegTot   [NH_*NSEG][4096] fp32   (totals -> exclusive prefix in pass B)
  //  IntraPre [NH_*NC_ ][4096] bf16   (per-chunk intra-segment exclusive prefix)
  //  KsegTot  [NH_*NSEG][64]   fp32
  //  KintraPre[NH_*NC_ ][64]   fp32
  const size_t segtot_e = (size_t)NH_ * NSEG * 4096;
  const size_t intra_e  = (size_t)NH_ * NC_ * 4096;
  const size_t kseg_e   = (size_t)NH_ * NSEG * 64;
  const size_t kintra_e = (size_t)NH_ * NC_ * 64;
  const size_t need = segtot_e * 4 + intra_e * 2 + kseg_e * 4 + kintra_e * 4;
  if (ws_size < need) return;
  float* SegTot = (float*)d_ws;
  unsigned short* IntraPre = (unsigned short*)(SegTot + segtot_e);
  float* KsegTot = (float*)(IntraPre + intra_e);
  float* KintraPre = KsegTot + kseg_e;

  hipLaunchKernelGGL(k_seg_sums, dim3(NH_ * NSEG), dim3(256), 0, stream,
                     keys, values, SegTot, IntraPre, KsegTot, KintraPre);
  hipLaunchKernelGGL(k_prefix, dim3(512 + 8), dim3(256), 0, stream, SegTot, KsegTot);
  hipLaunchKernelGGL(k_output, dim3(NH_ * NC_), dim3(256), 0, stream,
                     queries, keys, values, SegTot, IntraPre, KsegTot, KintraPre, out);
}